// Round 13
// baseline (173.182 us; speedup 1.0000x reference)
//
#include <hip/hip_runtime.h>
#include <stdint.h>

// Problem constants (fixed by setup_inputs)
#define NB 16
#define NTF 4096      // frames T
#define ND 512        // feature dim D
#define NS 8192       // note_size (= 2*T)
#define NCOL 40       // 5 + 10 + 25 output columns
#define ROWSB 64      // rows per block (lane = row)
#define BLOCK 512     // 8 waves
#define CPW 5         // cols per wave
#define CD 32         // chunk depth (floats of d)
#define NCH 16        // 512 / 32
#define LGS 65        // Lg row stride

typedef float v4f __attribute__((ext_vector_type(4)));

// W pack (round-5 verbatim, proven): Wp[(u*8 + w)*20 + c*4 + dl] = W[d=u*4+dl][col=w*5+c]
// -> per (wave w, 4-d unit u) slice is 20 contiguous floats (80 B) = 5 dwordx4;
//    stream stride per u is 160 floats (8 waves interleaved).
extern "C" __global__ void pack_w_kernel(const float* __restrict__ Wg,
                                         const float* __restrict__ Wt,
                                         const float* __restrict__ Wf,
                                         float* __restrict__ Wp)
{
    int o = blockIdx.x * 256 + threadIdx.x;
    if (o >= NCOL * ND) return;
    int s20 = o / 20, r = o % 20;
    int c = r >> 2, dl = r & 3;
    int u = s20 >> 3, w = s20 & 7;
    int d = u * 4 + dl, col = w * 5 + c;
    float v;
    if (col < 5)       v = Wg[d * 5  + col];
    else if (col < 15) v = Wt[d * 10 + (col - 5)];
    else               v = Wf[d * 25 + (col - 15)];
    Wp[o] = v;
}

#define GLDS(gp, lp) __builtin_amdgcn_global_load_lds( \
    (const __attribute__((address_space(1))) unsigned int*)(gp), \
    (__attribute__((address_space(3))) unsigned int*)(lp), 16, 0, 0)

// ALL data-carrying memory ops are compiler-owned (exact counted waits):
//   x: GLDS -> LDS (r5-proven staging), visibility via vmcnt(0)+s_barrier
//      (vmcnt(0) is unconditionally safe: drains ours AND the compiler's).
//   W: plain C++ vector loads with r9-proven opaque-z0 address (compiler
//      cannot scalarize to s_load; emits global_load_dwordx4 + its own
//      counted vmcnt waits), one-sub-ahead source pipeline (wA <- wB).
//   x LDS reads: compiler ds_reads, use-waited before each barrier -> the
//      2-buffer rotation is race-free.
extern "C" __global__ void __launch_bounds__(BLOCK, 6)
hier_main(const float* __restrict__ x,
          const float* __restrict__ bg, const float* __restrict__ bt,
          const float* __restrict__ bf,
          const float* __restrict__ Wp, float* __restrict__ out)
{
    __shared__ __align__(16) float xs[2][ROWSB * CD];   // 2 x 8KB x-chunk buffers
    __shared__ float Lg[NCOL * LGS];                    // logits [c][row], 10.4 KB

    const int t    = threadIdx.x;
    const int lane = t & 63;
    const int w    = t >> 6;                            // wave 0..7
    const int row0 = blockIdx.x * ROWSB;
    const int wu   = __builtin_amdgcn_readfirstlane(w);

    // opaque zero: keeps the W address un-provably-uniform -> vector loads
    int z0;
    asm("v_mov_b32 %0, 0" : "=v"(z0));
    const float* wv = Wp + wu * 20 + z0;                // wave's W stream base

    float acc[CPW];
#pragma unroll
    for (int j = 0; j < CPW; ++j) acc[j] = 0.f;

    // stage: wave w loads its 1KB slice (dq = w) of chunk ch into buffer p
    // (r5 verbatim; slot j*64+lane -> reads are base+lane*16B, conflict-free)
    auto stage = [&](int ch_, int p_) {
        const float* gp = x + (size_t)(row0 + lane) * ND + ch_ * CD + wu * 4;
        GLDS(gp, (char*)&xs[p_][0] + (size_t)wu * 1024);
    };

    stage(0, 0);

#pragma unroll 1
    for (int ch = 0; ch < NCH; ++ch) {
        asm volatile("s_waitcnt vmcnt(0)" ::: "memory");    // drain stage(ch) (+any W): safe
        __builtin_amdgcn_s_barrier();                       // chunk ch visible block-wide
        if (ch < NCH - 1) stage(ch + 1, (ch + 1) & 1);      // into the buffer consumed at ch-1

        const float* xb = &xs[ch & 1][0];
        const float* wc = wv + (size_t)ch * 1280;           // this chunk's 8 W sub-slices

        v4f wA[CPW], wB[CPW], xA, xB;
#pragma unroll
        for (int j = 0; j < CPW; ++j) wA[j] = *(const v4f*)(wc + j * 4);
        xA = *(const v4f*)(xb + (size_t)lane * 4);

#pragma unroll
        for (int q = 0; q < 8; ++q) {
            if (q < 7) {                                    // prefetch sub q+1 (compiler-counted)
#pragma unroll
                for (int j = 0; j < CPW; ++j)
                    wB[j] = *(const v4f*)(wc + (size_t)(q + 1) * 160 + j * 4);
                xB = *(const v4f*)(xb + (size_t)((q + 1) * 64 + lane) * 4);
            }
#pragma unroll
            for (int j = 0; j < CPW; ++j) {                 // 20 FMAs on current operands
                float a = acc[j];
                a = fmaf(xA.x, wA[j].x, a);
                a = fmaf(xA.y, wA[j].y, a);
                a = fmaf(xA.z, wA[j].z, a);
                a = fmaf(xA.w, wA[j].w, a);
                acc[j] = a;
            }
            if (q < 7) {
#pragma unroll
                for (int j = 0; j < CPW; ++j) wA[j] = wB[j];   // SSA rename
                xA = xB;
            }
        }
    }

    // ---- share logits: Lg[col][row] (lane-consecutive: conflict-free) ----
#pragma unroll
    for (int j = 0; j < CPW; ++j) Lg[(wu * CPW + j) * LGS + lane] = acc[j];
    __syncthreads();

    // ---- phase A: per-row bias + hierarchical argmax chain (wave 0) ----
    if (t < ROWSB) {
        constexpr int TOWN[10] = {0,1,2,2,2,3,3,3,4,4};
        constexpr int FOWN[25] = {0,1,2,2,2,3,3,3,3,3,3,3,3,4,9,6,8,5,7,1,3,3,3,9,3};
        const int r = t;
        float gl[5]; int gp = 0; float gbest = -INFINITY;
#pragma unroll
        for (int c = 0; c < 5; ++c) {
            float v = Lg[c * LGS + r] + bg[c];
            gl[c] = v;
            if (v > gbest) { gbest = v; gp = c; }   // strict > == jnp.argmax first-max
        }
        float tl[10]; int tp = 0; float tbest = -INFINITY;
#pragma unroll
        for (int k = 0; k < 10; ++k) {
            float v = (Lg[(5 + k) * LGS + r] + bt[k]) * ((TOWN[k] == gp) ? 1.f : 0.f);
            tl[k] = v;
            if (v > tbest) { tbest = v; tp = k; }
        }
#pragma unroll
        for (int c = 0; c < 5; ++c)  Lg[c * LGS + r] = gl[c];
#pragma unroll
        for (int k = 0; k < 10; ++k) Lg[(5 + k) * LGS + r] = tl[k];
#pragma unroll
        for (int f = 0; f < 25; ++f) {
            float v = (Lg[(15 + f) * LGS + r] + bf[f]) * ((FOWN[f] == tp) ? 1.f : 0.f);
            Lg[(15 + f) * LGS + r] = v;
        }
    }
    __syncthreads();

    // ---- phase B: FULLY COALESCED linear stores (consecutive t -> consecutive
    // floats): each 128B line written back-to-back by one wave ----
    const int b   = row0 >> 12;
    const int tt0 = row0 & (NTF - 1);

    {   // group_up [B][S][5]: 128 frames x 5 = 640 floats
        float* og = out + ((size_t)b * NS + 2 * (size_t)tt0) * 5;
        for (int i = t; i < 640; i += BLOCK) {
            int s = i / 5, c = i - s * 5;
            og[i] = Lg[c * LGS + (s >> 1)];
        }
    }
    {   // tech_up [B][S][10]: 1280 floats
        float* ot = out + (size_t)NB * NS * 5 + ((size_t)b * NS + 2 * (size_t)tt0) * 10;
        for (int i = t; i < 1280; i += BLOCK) {
            int s = i / 10, c = i - s * 10;
            ot[i] = Lg[(5 + c) * LGS + (s >> 1)];
        }
    }
    {   // final_up [B][S][25]: 3200 floats
        float* of = out + (size_t)NB * NS * 15 + ((size_t)b * NS + 2 * (size_t)tt0) * 25;
        for (int i = t; i < 3200; i += BLOCK) {
            int s = i / 25, c = i - s * 25;
            of[i] = Lg[(15 + c) * LGS + (s >> 1)];
        }
    }
    {   // frame_level_final_tech_logits [B][T][25]: 1600 floats
        float* ofr = out + (size_t)NB * NS * 40 + ((size_t)b * NTF + tt0) * 25;
        for (int i = t; i < 1600; i += BLOCK) {
            int s = i / 25, c = i - s * 25;
            ofr[i] = Lg[(15 + c) * LGS + s];
        }
    }
}

extern "C" void kernel_launch(void* const* d_in, const int* in_sizes, int n_in,
                              void* d_out, int out_size, void* d_ws, size_t ws_size,
                              hipStream_t stream)
{
    const float* x  = (const float*)d_in[0];
    const float* Wg = (const float*)d_in[1];
    const float* bg = (const float*)d_in[2];
    const float* Wt = (const float*)d_in[3];
    const float* bt = (const float*)d_in[4];
    const float* Wf = (const float*)d_in[5];
    const float* bf = (const float*)d_in[6];
    float* Wp   = (float*)d_ws;          // 40*512*4 = 80 KB packed weights
    float* outp = (float*)d_out;

    hipLaunchKernelGGL(pack_w_kernel, dim3((NCOL * ND + 255) / 256), dim3(256), 0, stream,
                       Wg, Wt, Wf, Wp);
    hipLaunchKernelGGL(hier_main, dim3((NB * NTF) / ROWSB), dim3(BLOCK), 0, stream,
                       x, bg, bt, bf, Wp, outp);
}